// Round 6
// baseline (87.101 us; speedup 1.0000x reference)
//
#include <hip/hip_runtime.h>
#include <math.h>

#define HH 1024
#define WW 1024
#define NB 8
#define ROWS 8                       // output rows per block (full 1024-wide band)
#define CHUNKS (HH / ROWS)           // 128
#define NBLK (NB * CHUNKS)           // 1024 blocks; 4 waves = 4 horizontal stripes

// ws layout: [0] ticket counter (unsigned, memset to 0 each call)
//            [8 .. 8+NBLK*8) block partials {Sp0,SLp0,Sp1,SLp1,N,NL,0,0}
__global__ __launch_bounds__(256, 4) void ul_fused(const float* __restrict__ pred,
                                                   const float* __restrict__ target,
                                                   unsigned* __restrict__ ticket,
                                                   float* __restrict__ partials,
                                                   float* __restrict__ out) {
    const int wv   = threadIdx.x >> 6;     // stripe 0..3
    const int lane = threadIdx.x & 63;
    const int b     = blockIdx.x >> 7;     // batch
    const int chunk = blockIdx.x & 127;
    const int r0    = chunk * ROWS;
    const int col4  = wv * 256 + lane * 4;

    const float* __restrict__ t1p = target + (size_t)(2 * b + 1) * (HH * WW);
    const float* __restrict__ p0p = pred   + (size_t)(2 * b)     * (HH * WW);
    const float* __restrict__ p1p = p0p + (size_t)(HH * WW);

    // ---- phase 1: ALL label loads (10 independent float4, nothing else) ----
    float4 vm[ROWS + 2];
    #pragma unroll
    for (int i = 0; i < ROWS + 2; ++i) {
        int h = r0 - 1 + i;
        h = h < 0 ? 0 : (h >= HH ? HH - 1 : h);
        vm[i] = *(const float4*)(t1p + (size_t)h * WW + col4);
    }

    // ---- phase 2: pack nibbles; neighbor bits via 2 shuffles of packed words ----
    unsigned long long ppack = 0;
    unsigned myL = 0, myR = 0;
    #pragma unroll
    for (int i = 0; i < ROWS + 2; ++i) {
        const unsigned p = (vm[i].x > 0.5f ? 1u : 0u) | (vm[i].y > 0.5f ? 2u : 0u) |
                           (vm[i].z > 0.5f ? 4u : 0u) | (vm[i].w > 0.5f ? 8u : 0u);
        ppack |= (unsigned long long)p << (4 * i);
        myL   |= (p & 1u) << i;
        myR   |= ((p >> 3) & 1u) << i;
    }
    const unsigned plpack = __shfl_up(myR, 1);     // left neighbor's col3 bits
    const unsigned prpack = __shfl_down(myL, 1);   // right neighbor's col0 bits

    // ---- in-block halo exchange across the 4 stripes of this row band ----
    __shared__ unsigned eL[4], eR[4];
    const unsigned lbm = __shfl(myL, 0);
    const unsigned rbm = __shfl(myR, 63);
    if (lane == 0) { eL[wv] = lbm; eR[wv] = rbm; }
    __syncthreads();
    const unsigned Lh = (wv > 0) ? eR[wv - 1] : lbm;   // clamp at image edge
    const unsigned Rh = (wv < 3) ? eL[wv + 1] : rbm;
    const unsigned PL = (lane == 0)  ? Lh : plpack;
    const unsigned PR = (lane == 63) ? Rh : prpack;

    // ---- phase 3a: 6-bit windows -> per-row uniformity nibbles ----
    unsigned w6[ROWS + 2];
    #pragma unroll
    for (int i = 0; i < ROWS + 2; ++i) {
        const unsigned p = (unsigned)(ppack >> (4 * i)) & 0xFu;
        w6[i] = ((PL >> i) & 1u) | (p << 1) | (((PR >> i) & 1u) << 5);
    }
    unsigned unis = 0;
    #pragma unroll
    for (int j = 0; j < ROWS; ++j) {
        const unsigned A = w6[j] & w6[j + 1] & w6[j + 2];
        const unsigned O = w6[j] | w6[j + 1] | w6[j + 2];
        unis |= (((A & (A >> 1) & (A >> 2)) | ~(O | (O >> 1) | (O >> 2))) & 0xFu) << (4 * j);
    }

    // ---- phase 3b: gather — branch bodies contain ONLY loads ----
    float4 x0[ROWS], x1[ROWS];
    #pragma unroll
    for (int j = 0; j < ROWS; ++j) {
        if ((unis >> (4 * j)) & 0xFu) {
            const size_t off = (size_t)(r0 + j) * WW + col4;
            x0[j] = *(const float4*)(p0p + off);
            x1[j] = *(const float4*)(p1p + off);
        }
    }

    // ---- phase 3c: consume ----
    float s_p0 = 0.f, s_lp0 = 0.f, s_p1 = 0.f, s_lp1 = 0.f;
    int nC = 0, nL = 0;
    #pragma unroll
    for (int j = 0; j < ROWS; ++j) {
        const unsigned uni = (unis >> (4 * j)) & 0xFu;
        if (uni) {
            const unsigned lb4 = (unsigned)(ppack >> (4 * (j + 1))) & 0xFu;
            nC += __popc(uni);
            nL += __popc(uni & lb4);
            #define UL_DO_K(K, C0, C1)                                          \
                if ((uni >> K) & 1u) {                                          \
                    float sg0 = 1.0f / (1.0f + expf(-(C0)));                    \
                    float sg1 = 1.0f / (1.0f + expf(-(C1)));                    \
                    sg0 = fminf(fmaxf(sg0, 1e-7f), 1.0f - 1e-7f);               \
                    sg1 = fminf(fmaxf(sg1, 1e-7f), 1.0f - 1e-7f);               \
                    s_p0 += sg0; s_p1 += sg1;                                   \
                    if ((lb4 >> K) & 1u) { s_lp0 += sg0; s_lp1 += sg1; }        \
                }
            UL_DO_K(0, x0[j].x, x1[j].x)
            UL_DO_K(1, x0[j].y, x1[j].y)
            UL_DO_K(2, x0[j].z, x1[j].z)
            UL_DO_K(3, x0[j].w, x1[j].w)
            #undef UL_DO_K
        }
    }

    // ---- wave reduce (4 floats + 2 ints) ----
    #pragma unroll
    for (int off = 32; off; off >>= 1) {
        s_p0  += __shfl_xor(s_p0,  off, 64);
        s_lp0 += __shfl_xor(s_lp0, off, 64);
        s_p1  += __shfl_xor(s_p1,  off, 64);
        s_lp1 += __shfl_xor(s_lp1, off, 64);
        nC    += __shfl_xor(nC,    off, 64);
        nL    += __shfl_xor(nL,    off, 64);
    }

    __shared__ float sm[4][6];
    if (lane == 0) {
        sm[wv][0] = s_p0;  sm[wv][1] = s_lp0;
        sm[wv][2] = s_p1;  sm[wv][3] = s_lp1;
        sm[wv][4] = (float)nC; sm[wv][5] = (float)nL;
    }
    __syncthreads();
    if (threadIdx.x < 8) {
        const int k = threadIdx.x;
        const float v = (k < 6) ? (sm[0][k] + sm[1][k] + sm[2][k] + sm[3][k]) : 0.0f;
        partials[(size_t)blockIdx.x * 8 + k] = v;
    }

    // ---- last-block final reduction (threadFenceReduction pattern) ----
    __threadfence();                        // make this block's partial device-visible
    __syncthreads();
    __shared__ int lastFlag;
    if (threadIdx.x == 0) {
        const unsigned old = atomicAdd(ticket, 1u);
        lastFlag = (old == (unsigned)(NBLK - 1));
    }
    __syncthreads();
    if (!lastFlag) return;
    __threadfence();                        // acquire: see all blocks' partials

    const int t = threadIdx.x;
    float a0 = 0.f, a1 = 0.f, a2 = 0.f, a3 = 0.f;
    #pragma unroll
    for (int r = 0; r < 8; ++r) {           // 2048 float4s = NBLK*8 floats
        const float4 v = ((const float4*)partials)[t + 256 * r];
        a0 += v.x; a1 += v.y; a2 += v.z; a3 += v.w;
    }
    // butterfly keeping parity class (even t = {Sp0,SLp0,Sp1,SLp1}, odd t = {N,NL,0,0})
    #pragma unroll
    for (int off = 32; off >= 2; off >>= 1) {
        a0 += __shfl_xor(a0, off, 64); a1 += __shfl_xor(a1, off, 64);
        a2 += __shfl_xor(a2, off, 64); a3 += __shfl_xor(a3, off, 64);
    }
    __shared__ float fm[4][2][4];
    if (lane < 2) {
        fm[wv][lane][0] = a0; fm[wv][lane][1] = a1;
        fm[wv][lane][2] = a2; fm[wv][lane][3] = a3;
    }
    __syncthreads();
    if (t == 0) {
        float Sp0 = 0.f, SLp0 = 0.f, Sp1 = 0.f, SLp1 = 0.f, N = 0.f, NL = 0.f;
        #pragma unroll
        for (int w = 0; w < 4; ++w) {
            Sp0 += fm[w][0][0]; SLp0 += fm[w][0][1];
            Sp1 += fm[w][0][2]; SLp1 += fm[w][0][3];
            N   += fm[w][1][0]; NL   += fm[w][1][1];
        }
        const float tp0 = 0.95f * Sp0 - 0.9f * SLp0;
        const float st0 = 0.95f * N   - 0.9f * NL;
        const float fn0 = st0 - tp0;
        const float fp0 = Sp0 - tp0;
        const float tp1 = 0.05f * Sp1 + 0.9f * SLp1;
        const float st1 = 0.05f * N   + 0.9f * NL;
        const float fn1 = st1 - tp1;
        const float fp1 = Sp1 - tp1;
        const float d0 = (tp0 + 1e-7f) / (tp0 + 0.6f * fn0 + 0.4f * fp0 + 1e-7f);
        const float d1 = (tp1 + 1e-7f) / (tp1 + 0.6f * fn1 + 0.4f * fp1 + 1e-7f);
        const float back = 1.0f - d0;
        const float fore = sqrtf(fmaxf(1.0f - d1, 0.0f));   // (1-d)*(1-d)^-0.5
        out[0] = 0.5f * (back + fore);                       // WEIGHT=1 kills CE term
    }
}

extern "C" void kernel_launch(void* const* d_in, const int* in_sizes, int n_in,
                              void* d_out, int out_size, void* d_ws, size_t ws_size,
                              hipStream_t stream) {
    const float* pred   = (const float*)d_in[0];
    const float* target = (const float*)d_in[1];
    unsigned* ticket  = (unsigned*)d_ws;
    float*    partials = (float*)d_ws + 8;   // 32B-aligned, NBLK*8 floats
    float*    out      = (float*)d_out;

    hipMemsetAsync(d_ws, 0, sizeof(unsigned), stream);   // ticket = 0 each call
    ul_fused<<<NBLK, 256, 0, stream>>>(pred, target, ticket, partials, out);
}

// Round 7
// 32.573 us; speedup vs baseline: 2.6740x; 2.6740x over previous
//
#include <hip/hip_runtime.h>
#include <math.h>

#define HH 1024
#define WW 1024
#define NB 8
#define ROWS 8                       // output rows per block (full 1024-wide band)
#define CHUNKS (HH / ROWS)           // 128
#define NBLK (NB * CHUNKS)           // 1024 blocks; 4 waves = 4 horizontal stripes
#define NSLOT 32                     // contention-spreading factor
#define FSCALE 16777216.0            // 2^24 fixed-point scale for float sums

// ws layout (bytes):
//   [0]         u32 ticket            (zeroed each call)
//   [64]        u64 fslots[4][NSLOT]  (Sp0,SLp0,Sp1,SLp1 scaled by 2^24)
//   [64+1024]   u32 nslots[2][NSLOT]  (N, NL)
// memset 64+1024+256 = 1344 bytes each call.
__global__ __launch_bounds__(256, 4) void ul_fused(const float* __restrict__ pred,
                                                   const float* __restrict__ target,
                                                   unsigned* __restrict__ ticket,
                                                   unsigned long long* __restrict__ fslots,
                                                   unsigned* __restrict__ nslots,
                                                   float* __restrict__ out) {
    const int wv   = threadIdx.x >> 6;     // stripe 0..3
    const int lane = threadIdx.x & 63;
    const int b     = blockIdx.x >> 7;     // batch
    const int chunk = blockIdx.x & 127;
    const int r0    = chunk * ROWS;
    const int col4  = wv * 256 + lane * 4;

    const float* __restrict__ t1p = target + (size_t)(2 * b + 1) * (HH * WW);
    const float* __restrict__ p0p = pred   + (size_t)(2 * b)     * (HH * WW);
    const float* __restrict__ p1p = p0p + (size_t)(HH * WW);

    // ---- phase 1: ALL label loads (10 independent float4, nothing else) ----
    float4 vm[ROWS + 2];
    #pragma unroll
    for (int i = 0; i < ROWS + 2; ++i) {
        int h = r0 - 1 + i;
        h = h < 0 ? 0 : (h >= HH ? HH - 1 : h);
        vm[i] = *(const float4*)(t1p + (size_t)h * WW + col4);
    }

    // ---- phase 2: pack nibbles; neighbor bits via 2 shuffles of packed words ----
    unsigned long long ppack = 0;
    unsigned myL = 0, myR = 0;
    #pragma unroll
    for (int i = 0; i < ROWS + 2; ++i) {
        const unsigned p = (vm[i].x > 0.5f ? 1u : 0u) | (vm[i].y > 0.5f ? 2u : 0u) |
                           (vm[i].z > 0.5f ? 4u : 0u) | (vm[i].w > 0.5f ? 8u : 0u);
        ppack |= (unsigned long long)p << (4 * i);
        myL   |= (p & 1u) << i;
        myR   |= ((p >> 3) & 1u) << i;
    }
    const unsigned plpack = __shfl_up(myR, 1);     // left neighbor's col3 bits
    const unsigned prpack = __shfl_down(myL, 1);   // right neighbor's col0 bits

    // ---- in-block halo exchange across the 4 stripes of this row band ----
    __shared__ unsigned eL[4], eR[4];
    const unsigned lbm = __shfl(myL, 0);
    const unsigned rbm = __shfl(myR, 63);
    if (lane == 0) { eL[wv] = lbm; eR[wv] = rbm; }
    __syncthreads();
    const unsigned Lh = (wv > 0) ? eR[wv - 1] : lbm;   // clamp at image edge
    const unsigned Rh = (wv < 3) ? eL[wv + 1] : rbm;
    const unsigned PL = (lane == 0)  ? Lh : plpack;
    const unsigned PR = (lane == 63) ? Rh : prpack;

    // ---- phase 3a: 6-bit windows -> per-row uniformity nibbles ----
    unsigned w6[ROWS + 2];
    #pragma unroll
    for (int i = 0; i < ROWS + 2; ++i) {
        const unsigned p = (unsigned)(ppack >> (4 * i)) & 0xFu;
        w6[i] = ((PL >> i) & 1u) | (p << 1) | (((PR >> i) & 1u) << 5);
    }
    unsigned unis = 0;
    #pragma unroll
    for (int j = 0; j < ROWS; ++j) {
        const unsigned A = w6[j] & w6[j + 1] & w6[j + 2];
        const unsigned O = w6[j] | w6[j + 1] | w6[j + 2];
        unis |= (((A & (A >> 1) & (A >> 2)) | ~(O | (O >> 1) | (O >> 2))) & 0xFu) << (4 * j);
    }

    // ---- phase 3b: gather — branch bodies contain ONLY loads ----
    float4 x0[ROWS], x1[ROWS];
    #pragma unroll
    for (int j = 0; j < ROWS; ++j) {
        if ((unis >> (4 * j)) & 0xFu) {
            const size_t off = (size_t)(r0 + j) * WW + col4;
            x0[j] = *(const float4*)(p0p + off);
            x1[j] = *(const float4*)(p1p + off);
        }
    }
    // keep the gather loads hoisted: forbid sinking them into the consume branches
    asm volatile("" ::: "memory");
    __builtin_amdgcn_sched_barrier(0);

    // ---- phase 3c: consume ----
    float s_p0 = 0.f, s_lp0 = 0.f, s_p1 = 0.f, s_lp1 = 0.f;
    int nC = 0, nL = 0;
    #pragma unroll
    for (int j = 0; j < ROWS; ++j) {
        const unsigned uni = (unis >> (4 * j)) & 0xFu;
        if (uni) {
            const unsigned lb4 = (unsigned)(ppack >> (4 * (j + 1))) & 0xFu;
            nC += __popc(uni);
            nL += __popc(uni & lb4);
            #define UL_DO_K(K, C0, C1)                                          \
                if ((uni >> K) & 1u) {                                          \
                    float sg0 = 1.0f / (1.0f + expf(-(C0)));                    \
                    float sg1 = 1.0f / (1.0f + expf(-(C1)));                    \
                    sg0 = fminf(fmaxf(sg0, 1e-7f), 1.0f - 1e-7f);               \
                    sg1 = fminf(fmaxf(sg1, 1e-7f), 1.0f - 1e-7f);               \
                    s_p0 += sg0; s_p1 += sg1;                                   \
                    if ((lb4 >> K) & 1u) { s_lp0 += sg0; s_lp1 += sg1; }        \
                }
            UL_DO_K(0, x0[j].x, x1[j].x)
            UL_DO_K(1, x0[j].y, x1[j].y)
            UL_DO_K(2, x0[j].z, x1[j].z)
            UL_DO_K(3, x0[j].w, x1[j].w)
            #undef UL_DO_K
        }
    }

    // ---- wave reduce (4 floats + 2 ints) ----
    #pragma unroll
    for (int off = 32; off; off >>= 1) {
        s_p0  += __shfl_xor(s_p0,  off, 64);
        s_lp0 += __shfl_xor(s_lp0, off, 64);
        s_p1  += __shfl_xor(s_p1,  off, 64);
        s_lp1 += __shfl_xor(s_lp1, off, 64);
        nC    += __shfl_xor(nC,    off, 64);
        nL    += __shfl_xor(nL,    off, 64);
    }

    __shared__ float sm[4][6];
    if (lane == 0) {
        sm[wv][0] = s_p0;  sm[wv][1] = s_lp0;
        sm[wv][2] = s_p1;  sm[wv][3] = s_lp1;
        sm[wv][4] = (float)nC; sm[wv][5] = (float)nL;
    }
    __syncthreads();

    // ---- publish block partials via device-coherent atomics (NO fences) ----
    __shared__ int lastFlag;
    if (threadIdx.x < 64) {                          // wave 0 only
        if (lane < 6) {
            const int k = lane;
            const float v = sm[0][k] + sm[1][k] + sm[2][k] + sm[3][k];
            const int s = blockIdx.x & (NSLOT - 1);
            if (k < 4) {
                // deterministic: fixed-point u64, integer atomics commute exactly
                const unsigned long long q =
                    (unsigned long long)(long long)((double)v * FSCALE + 0.5);
                atomicAdd(&fslots[k * NSLOT + s], q);
            } else {
                atomicAdd(&nslots[(k - 4) * NSLOT + s], (unsigned)(v + 0.5f));
            }
        }
        // order: partial-adds acked at coherent point BEFORE ticket bump
        asm volatile("s_waitcnt vmcnt(0)" ::: "memory");
        if (lane == 0) {
            const unsigned old = atomicAdd(ticket, 1u);
            lastFlag = (old == (unsigned)(NBLK - 1));
        }
    }
    __syncthreads();
    if (!lastFlag) return;

    // ---- last block: read slots back via atomic RMW reads, epilogue ----
    const int t = threadIdx.x;
    double v = 0.0;
    if (t < 128) {
        const unsigned long long u = atomicAdd(&fslots[t], 0ull);
        v = (double)(long long)u * (1.0 / FSCALE);
    } else if (t < 192) {
        v = (double)atomicAdd(&nslots[t - 128], 0u);
    }
    #pragma unroll
    for (int off = 16; off; off >>= 1) v += __shfl_xor(v, off, 64);
    __shared__ double fin[6];
    if (t < 192 && (t & 31) == 0) fin[t >> 5] = v;   // q = 0..5
    __syncthreads();
    if (t == 0) {
        const float Sp0 = (float)fin[0], SLp0 = (float)fin[1];
        const float Sp1 = (float)fin[2], SLp1 = (float)fin[3];
        const float N   = (float)fin[4], NL   = (float)fin[5];
        const float tp0 = 0.95f * Sp0 - 0.9f * SLp0;
        const float st0 = 0.95f * N   - 0.9f * NL;
        const float fn0 = st0 - tp0;
        const float fp0 = Sp0 - tp0;
        const float tp1 = 0.05f * Sp1 + 0.9f * SLp1;
        const float st1 = 0.05f * N   + 0.9f * NL;
        const float fn1 = st1 - tp1;
        const float fp1 = Sp1 - tp1;
        const float d0 = (tp0 + 1e-7f) / (tp0 + 0.6f * fn0 + 0.4f * fp0 + 1e-7f);
        const float d1 = (tp1 + 1e-7f) / (tp1 + 0.6f * fn1 + 0.4f * fp1 + 1e-7f);
        const float back = 1.0f - d0;
        const float fore = sqrtf(fmaxf(1.0f - d1, 0.0f));   // (1-d)*(1-d)^-0.5
        out[0] = 0.5f * (back + fore);                       // WEIGHT=1 kills CE term
    }
}

extern "C" void kernel_launch(void* const* d_in, const int* in_sizes, int n_in,
                              void* d_out, int out_size, void* d_ws, size_t ws_size,
                              hipStream_t stream) {
    const float* pred   = (const float*)d_in[0];
    const float* target = (const float*)d_in[1];
    unsigned char* ws = (unsigned char*)d_ws;
    unsigned*           ticket = (unsigned*)ws;
    unsigned long long* fslots = (unsigned long long*)(ws + 64);        // 4*32 u64
    unsigned*           nslots = (unsigned*)(ws + 64 + 1024);           // 2*32 u32
    float*              out    = (float*)d_out;

    hipMemsetAsync(d_ws, 0, 1344, stream);   // ticket + slots = 0 each call
    ul_fused<<<NBLK, 256, 0, stream>>>(pred, target, ticket, fslots, nslots, out);
}

// Round 8
// 29.620 us; speedup vs baseline: 2.9406x; 1.0997x over previous
//
#include <hip/hip_runtime.h>
#include <math.h>

#define HH 1024
#define WW 1024
#define NB 8
#define ROWS 8                       // output rows per block (full 1024-wide band)
#define CHUNKS (HH / ROWS)           // 128
#define NBLK (NB * CHUNKS)           // 1024 blocks; 4 waves = 4 horizontal stripes
#define NSLOT 32                     // contention-spreading factor
#define NGRP 32                      // ticket-tree groups (32 blocks each)
#define FSCALE 16777216.0            // 2^24 fixed-point scale for float sums

// ws layout (bytes), memset 1536 each call:
//   [0]     u32 master ticket
//   [128]   u32 subticket[NGRP]
//   [256]   u64 fslots[4][NSLOT]   (Sp0,SLp0,Sp1,SLp1 scaled by 2^24)
//   [1280]  u32 nslots[2][NSLOT]   (N, NL)
__global__ __launch_bounds__(256, 4) void ul_fused(const float* __restrict__ pred,
                                                   const float* __restrict__ target,
                                                   unsigned* __restrict__ master,
                                                   unsigned* __restrict__ subticket,
                                                   unsigned long long* __restrict__ fslots,
                                                   unsigned* __restrict__ nslots,
                                                   float* __restrict__ out) {
    const int wv   = threadIdx.x >> 6;     // stripe 0..3
    const int lane = threadIdx.x & 63;
    const int b     = blockIdx.x >> 7;     // batch
    const int chunk = blockIdx.x & 127;
    const int r0    = chunk * ROWS;
    const int col4  = wv * 256 + lane * 4;

    const float* __restrict__ t1p = target + (size_t)(2 * b + 1) * (HH * WW);
    const float* __restrict__ p0p = pred   + (size_t)(2 * b)     * (HH * WW);
    const float* __restrict__ p1p = p0p + (size_t)(HH * WW);

    // ---- phase 1: ALL label loads (10 independent float4, nothing else) ----
    float4 vm[ROWS + 2];
    #pragma unroll
    for (int i = 0; i < ROWS + 2; ++i) {
        int h = r0 - 1 + i;
        h = h < 0 ? 0 : (h >= HH ? HH - 1 : h);
        vm[i] = *(const float4*)(t1p + (size_t)h * WW + col4);
    }

    // ---- phase 2: pack nibbles; neighbor bits via 2 shuffles of packed words ----
    unsigned long long ppack = 0;
    unsigned myL = 0, myR = 0;
    #pragma unroll
    for (int i = 0; i < ROWS + 2; ++i) {
        const unsigned p = (vm[i].x > 0.5f ? 1u : 0u) | (vm[i].y > 0.5f ? 2u : 0u) |
                           (vm[i].z > 0.5f ? 4u : 0u) | (vm[i].w > 0.5f ? 8u : 0u);
        ppack |= (unsigned long long)p << (4 * i);
        myL   |= (p & 1u) << i;
        myR   |= ((p >> 3) & 1u) << i;
    }
    const unsigned plpack = __shfl_up(myR, 1);     // left neighbor's col3 bits
    const unsigned prpack = __shfl_down(myL, 1);   // right neighbor's col0 bits

    // ---- in-block halo exchange across the 4 stripes of this row band ----
    __shared__ unsigned eL[4], eR[4];
    const unsigned lbm = __shfl(myL, 0);
    const unsigned rbm = __shfl(myR, 63);
    if (lane == 0) { eL[wv] = lbm; eR[wv] = rbm; }
    __syncthreads();
    const unsigned Lh = (wv > 0) ? eR[wv - 1] : lbm;   // clamp at image edge
    const unsigned Rh = (wv < 3) ? eL[wv + 1] : rbm;
    const unsigned PL = (lane == 0)  ? Lh : plpack;
    const unsigned PR = (lane == 63) ? Rh : prpack;

    // ---- phase 3a: 6-bit windows -> per-row uniformity nibbles ----
    unsigned w6[ROWS + 2];
    #pragma unroll
    for (int i = 0; i < ROWS + 2; ++i) {
        const unsigned p = (unsigned)(ppack >> (4 * i)) & 0xFu;
        w6[i] = ((PL >> i) & 1u) | (p << 1) | (((PR >> i) & 1u) << 5);
    }
    unsigned unis = 0;
    #pragma unroll
    for (int j = 0; j < ROWS; ++j) {
        const unsigned A = w6[j] & w6[j + 1] & w6[j + 2];
        const unsigned O = w6[j] | w6[j + 1] | w6[j + 2];
        unis |= (((A & (A >> 1) & (A >> 2)) | ~(O | (O >> 1) | (O >> 2))) & 0xFu) << (4 * j);
    }

    // ---- phase 3b: gather — branch bodies contain ONLY loads ----
    float4 x0[ROWS], x1[ROWS];
    #pragma unroll
    for (int j = 0; j < ROWS; ++j) {
        if ((unis >> (4 * j)) & 0xFu) {
            const size_t off = (size_t)(r0 + j) * WW + col4;
            x0[j] = *(const float4*)(p0p + off);
            x1[j] = *(const float4*)(p1p + off);
        }
    }
    // keep the gather loads hoisted: forbid sinking them into the consume branches
    asm volatile("" ::: "memory");
    __builtin_amdgcn_sched_barrier(0);

    // ---- phase 3c: consume ----
    float s_p0 = 0.f, s_lp0 = 0.f, s_p1 = 0.f, s_lp1 = 0.f;
    int nC = 0, nL = 0;
    #pragma unroll
    for (int j = 0; j < ROWS; ++j) {
        const unsigned uni = (unis >> (4 * j)) & 0xFu;
        if (uni) {
            const unsigned lb4 = (unsigned)(ppack >> (4 * (j + 1))) & 0xFu;
            nC += __popc(uni);
            nL += __popc(uni & lb4);
            #define UL_DO_K(K, C0, C1)                                          \
                if ((uni >> K) & 1u) {                                          \
                    float sg0 = 1.0f / (1.0f + expf(-(C0)));                    \
                    float sg1 = 1.0f / (1.0f + expf(-(C1)));                    \
                    sg0 = fminf(fmaxf(sg0, 1e-7f), 1.0f - 1e-7f);               \
                    sg1 = fminf(fmaxf(sg1, 1e-7f), 1.0f - 1e-7f);               \
                    s_p0 += sg0; s_p1 += sg1;                                   \
                    if ((lb4 >> K) & 1u) { s_lp0 += sg0; s_lp1 += sg1; }        \
                }
            UL_DO_K(0, x0[j].x, x1[j].x)
            UL_DO_K(1, x0[j].y, x1[j].y)
            UL_DO_K(2, x0[j].z, x1[j].z)
            UL_DO_K(3, x0[j].w, x1[j].w)
            #undef UL_DO_K
        }
    }

    // ---- wave reduce (4 floats + 2 ints) ----
    #pragma unroll
    for (int off = 32; off; off >>= 1) {
        s_p0  += __shfl_xor(s_p0,  off, 64);
        s_lp0 += __shfl_xor(s_lp0, off, 64);
        s_p1  += __shfl_xor(s_p1,  off, 64);
        s_lp1 += __shfl_xor(s_lp1, off, 64);
        nC    += __shfl_xor(nC,    off, 64);
        nL    += __shfl_xor(nL,    off, 64);
    }

    __shared__ float sm[4][6];
    if (lane == 0) {
        sm[wv][0] = s_p0;  sm[wv][1] = s_lp0;
        sm[wv][2] = s_p1;  sm[wv][3] = s_lp1;
        sm[wv][4] = (float)nC; sm[wv][5] = (float)nL;
    }
    __syncthreads();

    // ---- publish block partials via device-coherent atomics (NO fences) ----
    __shared__ int lastFlag;
    if (threadIdx.x < 64) {                          // wave 0 only
        if (lane < 6) {
            const int k = lane;
            const float v = sm[0][k] + sm[1][k] + sm[2][k] + sm[3][k];
            const int s = blockIdx.x & (NSLOT - 1);
            if (k < 4) {
                // deterministic: fixed-point u64, integer atomics commute exactly
                const unsigned long long q =
                    (unsigned long long)(long long)((double)v * FSCALE + 0.5);
                atomicAdd(&fslots[k * NSLOT + s], q);
            } else {
                atomicAdd(&nslots[(k - 4) * NSLOT + s], (unsigned)(v + 0.5f));
            }
        }
        // order: slot-adds acked at the coherent point BEFORE any ticket bump
        asm volatile("s_waitcnt vmcnt(0)" ::: "memory");
        if (lane == 0) {
            lastFlag = 0;
            // two-level ticket tree: 32 groups x 32 blocks -> max 32-deep convoy
            const int g = blockIdx.x & (NGRP - 1);
            const unsigned so = atomicAdd(&subticket[g], 1u);
            if (so == 31u) {                           // group winner (32nd arriver)
                const unsigned mo = atomicAdd(master, 1u);
                lastFlag = (mo == (unsigned)(NGRP - 1));
            }
        }
    }
    __syncthreads();
    if (!lastFlag) return;

    // ---- last block: read slots back via atomic RMW reads, epilogue ----
    const int t = threadIdx.x;
    double v = 0.0;
    if (t < 128) {
        const unsigned long long u = atomicAdd(&fslots[t], 0ull);
        v = (double)(long long)u * (1.0 / FSCALE);
    } else if (t < 192) {
        v = (double)atomicAdd(&nslots[t - 128], 0u);
    }
    #pragma unroll
    for (int off = 16; off; off >>= 1) v += __shfl_xor(v, off, 64);
    __shared__ double fin[6];
    if (t < 192 && (t & 31) == 0) fin[t >> 5] = v;   // q = 0..5
    __syncthreads();
    if (t == 0) {
        const float Sp0 = (float)fin[0], SLp0 = (float)fin[1];
        const float Sp1 = (float)fin[2], SLp1 = (float)fin[3];
        const float N   = (float)fin[4], NL   = (float)fin[5];
        const float tp0 = 0.95f * Sp0 - 0.9f * SLp0;
        const float st0 = 0.95f * N   - 0.9f * NL;
        const float fn0 = st0 - tp0;
        const float fp0 = Sp0 - tp0;
        const float tp1 = 0.05f * Sp1 + 0.9f * SLp1;
        const float st1 = 0.05f * N   + 0.9f * NL;
        const float fn1 = st1 - tp1;
        const float fp1 = Sp1 - tp1;
        const float d0 = (tp0 + 1e-7f) / (tp0 + 0.6f * fn0 + 0.4f * fp0 + 1e-7f);
        const float d1 = (tp1 + 1e-7f) / (tp1 + 0.6f * fn1 + 0.4f * fp1 + 1e-7f);
        const float back = 1.0f - d0;
        const float fore = sqrtf(fmaxf(1.0f - d1, 0.0f));   // (1-d)*(1-d)^-0.5
        out[0] = 0.5f * (back + fore);                       // WEIGHT=1 kills CE term
    }
}

extern "C" void kernel_launch(void* const* d_in, const int* in_sizes, int n_in,
                              void* d_out, int out_size, void* d_ws, size_t ws_size,
                              hipStream_t stream) {
    const float* pred   = (const float*)d_in[0];
    const float* target = (const float*)d_in[1];
    unsigned char* ws = (unsigned char*)d_ws;
    unsigned*           master    = (unsigned*)ws;
    unsigned*           subticket = (unsigned*)(ws + 128);              // 32 u32
    unsigned long long* fslots    = (unsigned long long*)(ws + 256);    // 4*32 u64
    unsigned*           nslots    = (unsigned*)(ws + 1280);             // 2*32 u32
    float*              out       = (float*)d_out;

    hipMemsetAsync(d_ws, 0, 1536, stream);   // tickets + slots = 0 each call
    ul_fused<<<NBLK, 256, 0, stream>>>(pred, target, master, subticket,
                                       fslots, nslots, out);
}

// Round 9
// 21.247 us; speedup vs baseline: 4.0995x; 1.3941x over previous
//
#include <hip/hip_runtime.h>
#include <math.h>

#define HH 1024
#define WW 1024
#define NB 8
#define ROWS 8                       // output rows per block (full 1024-wide band)
#define CHUNKS (HH / ROWS)           // 128
#define NBLK (NB * CHUNKS)           // 1024 blocks; 4 waves = 4 horizontal stripes

// partials layout: ws[bid*8 + k], k = {Sp0, SLp0, Sp1, SLp1, N, NL, 0, 0}
__global__ __launch_bounds__(256, 4) void ul_main(const float* __restrict__ pred,
                                                  const float* __restrict__ target,
                                                  float* __restrict__ partials) {
    const int wv   = threadIdx.x >> 6;     // stripe 0..3
    const int lane = threadIdx.x & 63;
    const int b     = blockIdx.x >> 7;     // batch
    const int chunk = blockIdx.x & 127;
    const int r0    = chunk * ROWS;
    const int col4  = wv * 256 + lane * 4;

    const float* __restrict__ t1p = target + (size_t)(2 * b + 1) * (HH * WW);
    const float* __restrict__ p0p = pred   + (size_t)(2 * b)     * (HH * WW);
    const float* __restrict__ p1p = p0p + (size_t)(HH * WW);

    // ---- phase 1: ALL label loads (10 independent float4, nothing else) ----
    float4 vm[ROWS + 2];
    #pragma unroll
    for (int i = 0; i < ROWS + 2; ++i) {
        int h = r0 - 1 + i;
        h = h < 0 ? 0 : (h >= HH ? HH - 1 : h);
        vm[i] = *(const float4*)(t1p + (size_t)h * WW + col4);
    }

    // ---- phase 2: pack nibbles; neighbor bits via 2 shuffles of packed words ----
    unsigned long long ppack = 0;
    unsigned myL = 0, myR = 0;
    #pragma unroll
    for (int i = 0; i < ROWS + 2; ++i) {
        const unsigned p = (vm[i].x > 0.5f ? 1u : 0u) | (vm[i].y > 0.5f ? 2u : 0u) |
                           (vm[i].z > 0.5f ? 4u : 0u) | (vm[i].w > 0.5f ? 8u : 0u);
        ppack |= (unsigned long long)p << (4 * i);
        myL   |= (p & 1u) << i;
        myR   |= ((p >> 3) & 1u) << i;
    }
    const unsigned plpack = __shfl_up(myR, 1);     // left neighbor's col3 bits
    const unsigned prpack = __shfl_down(myL, 1);   // right neighbor's col0 bits

    // ---- in-block halo exchange across the 4 stripes of this row band ----
    __shared__ unsigned eL[4], eR[4];
    const unsigned lbm = __shfl(myL, 0);
    const unsigned rbm = __shfl(myR, 63);
    if (lane == 0) { eL[wv] = lbm; eR[wv] = rbm; }
    __syncthreads();
    const unsigned Lh = (wv > 0) ? eR[wv - 1] : lbm;   // clamp at image edge
    const unsigned Rh = (wv < 3) ? eL[wv + 1] : rbm;
    const unsigned PL = (lane == 0)  ? Lh : plpack;
    const unsigned PR = (lane == 63) ? Rh : prpack;

    // ---- phase 3a: 6-bit windows -> per-row uniformity nibbles ----
    unsigned w6[ROWS + 2];
    #pragma unroll
    for (int i = 0; i < ROWS + 2; ++i) {
        const unsigned p = (unsigned)(ppack >> (4 * i)) & 0xFu;
        w6[i] = ((PL >> i) & 1u) | (p << 1) | (((PR >> i) & 1u) << 5);
    }
    unsigned unis = 0;
    #pragma unroll
    for (int j = 0; j < ROWS; ++j) {
        const unsigned A = w6[j] & w6[j + 1] & w6[j + 2];
        const unsigned O = w6[j] | w6[j + 1] | w6[j + 2];
        unis |= (((A & (A >> 1) & (A >> 2)) | ~(O | (O >> 1) | (O >> 2))) & 0xFu) << (4 * j);
    }

    // ---- phase 3b: gather — branch bodies contain ONLY loads ----
    float4 x0[ROWS], x1[ROWS];
    #pragma unroll
    for (int j = 0; j < ROWS; ++j) {
        if ((unis >> (4 * j)) & 0xFu) {
            const size_t off = (size_t)(r0 + j) * WW + col4;
            x0[j] = *(const float4*)(p0p + off);
            x1[j] = *(const float4*)(p1p + off);
        }
    }
    // forbid sinking the gather loads into the consume branches: all rows' pred
    // loads must be in flight together (one vmcnt drain instead of ~5 serial)
    asm volatile("" ::: "memory");
    __builtin_amdgcn_sched_barrier(0);

    // ---- phase 3c: consume ----
    float s_p0 = 0.f, s_lp0 = 0.f, s_p1 = 0.f, s_lp1 = 0.f;
    int nC = 0, nL = 0;
    #pragma unroll
    for (int j = 0; j < ROWS; ++j) {
        const unsigned uni = (unis >> (4 * j)) & 0xFu;
        if (uni) {
            const unsigned lb4 = (unsigned)(ppack >> (4 * (j + 1))) & 0xFu;
            nC += __popc(uni);
            nL += __popc(uni & lb4);
            #define UL_DO_K(K, C0, C1)                                          \
                if ((uni >> K) & 1u) {                                          \
                    float sg0 = 1.0f / (1.0f + expf(-(C0)));                    \
                    float sg1 = 1.0f / (1.0f + expf(-(C1)));                    \
                    sg0 = fminf(fmaxf(sg0, 1e-7f), 1.0f - 1e-7f);               \
                    sg1 = fminf(fmaxf(sg1, 1e-7f), 1.0f - 1e-7f);               \
                    s_p0 += sg0; s_p1 += sg1;                                   \
                    if ((lb4 >> K) & 1u) { s_lp0 += sg0; s_lp1 += sg1; }        \
                }
            UL_DO_K(0, x0[j].x, x1[j].x)
            UL_DO_K(1, x0[j].y, x1[j].y)
            UL_DO_K(2, x0[j].z, x1[j].z)
            UL_DO_K(3, x0[j].w, x1[j].w)
            #undef UL_DO_K
        }
    }

    // ---- wave reduce (4 floats + 2 ints) ----
    #pragma unroll
    for (int off = 32; off; off >>= 1) {
        s_p0  += __shfl_xor(s_p0,  off, 64);
        s_lp0 += __shfl_xor(s_lp0, off, 64);
        s_p1  += __shfl_xor(s_p1,  off, 64);
        s_lp1 += __shfl_xor(s_lp1, off, 64);
        nC    += __shfl_xor(nC,    off, 64);
        nL    += __shfl_xor(nL,    off, 64);
    }

    __shared__ float sm[4][6];
    if (lane == 0) {
        sm[wv][0] = s_p0;  sm[wv][1] = s_lp0;
        sm[wv][2] = s_p1;  sm[wv][3] = s_lp1;
        sm[wv][4] = (float)nC; sm[wv][5] = (float)nL;
    }
    __syncthreads();
    if (threadIdx.x < 8) {
        const int k = threadIdx.x;
        const float v = (k < 6) ? (sm[0][k] + sm[1][k] + sm[2][k] + sm[3][k]) : 0.0f;
        partials[(size_t)blockIdx.x * 8 + k] = v;
    }
}

// Stage 2: reduce 1024 x 8 partials (float4, parity classes), compute scalar loss
__global__ __launch_bounds__(256) void ul_final(const float* __restrict__ ws,
                                                float* __restrict__ out) {
    const int t = threadIdx.x, lane = t & 63, wv = t >> 6;
    float a0 = 0.f, a1 = 0.f, a2 = 0.f, a3 = 0.f;
    #pragma unroll
    for (int r = 0; r < 8; ++r) {                 // 2048 float4s total
        const float4 v = ((const float4*)ws)[t + 256 * r];
        a0 += v.x; a1 += v.y; a2 += v.z; a3 += v.w;
    }
    // butterfly keeping parity class (even t = {Sp0,SLp0,Sp1,SLp1}, odd t = {N,NL,0,0})
    #pragma unroll
    for (int off = 32; off >= 2; off >>= 1) {
        a0 += __shfl_xor(a0, off, 64); a1 += __shfl_xor(a1, off, 64);
        a2 += __shfl_xor(a2, off, 64); a3 += __shfl_xor(a3, off, 64);
    }
    __shared__ float sm[4][2][4];
    if (lane < 2) {
        sm[wv][lane][0] = a0; sm[wv][lane][1] = a1;
        sm[wv][lane][2] = a2; sm[wv][lane][3] = a3;
    }
    __syncthreads();
    if (t == 0) {
        float Sp0 = 0.f, SLp0 = 0.f, Sp1 = 0.f, SLp1 = 0.f, N = 0.f, NL = 0.f;
        #pragma unroll
        for (int w = 0; w < 4; ++w) {
            Sp0 += sm[w][0][0]; SLp0 += sm[w][0][1];
            Sp1 += sm[w][0][2]; SLp1 += sm[w][0][3];
            N   += sm[w][1][0]; NL   += sm[w][1][1];
        }
        const float tp0 = 0.95f * Sp0 - 0.9f * SLp0;
        const float st0 = 0.95f * N   - 0.9f * NL;
        const float fn0 = st0 - tp0;
        const float fp0 = Sp0 - tp0;
        const float tp1 = 0.05f * Sp1 + 0.9f * SLp1;
        const float st1 = 0.05f * N   + 0.9f * NL;
        const float fn1 = st1 - tp1;
        const float fp1 = Sp1 - tp1;
        const float d0 = (tp0 + 1e-7f) / (tp0 + 0.6f * fn0 + 0.4f * fp0 + 1e-7f);
        const float d1 = (tp1 + 1e-7f) / (tp1 + 0.6f * fn1 + 0.4f * fp1 + 1e-7f);
        const float back = 1.0f - d0;
        const float fore = sqrtf(fmaxf(1.0f - d1, 0.0f));   // (1-d)*(1-d)^-0.5
        out[0] = 0.5f * (back + fore);                       // WEIGHT=1 kills CE term
    }
}

extern "C" void kernel_launch(void* const* d_in, const int* in_sizes, int n_in,
                              void* d_out, int out_size, void* d_ws, size_t ws_size,
                              hipStream_t stream) {
    const float* pred   = (const float*)d_in[0];
    const float* target = (const float*)d_in[1];
    float* partials = (float*)d_ws;    // 1024 * 8 floats = 32 KiB
    float* out      = (float*)d_out;

    ul_main<<<NBLK, 256, 0, stream>>>(pred, target, partials);
    ul_final<<<1, 256, 0, stream>>>(partials, out);
}